// Round 1
// baseline (1402.388 us; speedup 1.0000x reference)
//
#include <hip/hip_runtime.h>
#include <math.h>

#define N_ROWS 65536
#define CB 1024
#define SPLITS 4
#define JS (CB / SPLITS)   // 256 codebook entries per split

typedef float v4f __attribute__((ext_vector_type(4)));

// ---------------------------------------------------------------------------
// Exact emulation of numpy's pairwise_sum for n=64 fp32 (AVX-512 path):
//   r0..r3 = 16-lane vector loads; sum = (r0+r1)+(r2+r3);
//   then _mm512_reduce_add_ps tree: fold at lane distance 8, 4, 2, 1.
// fp contract OFF so the squares are not fused into the adds.
// ---------------------------------------------------------------------------
__device__ __forceinline__ float tree_sum64_sq(const float* x) {
#pragma clang fp contract(off)
    float sq[64];
#pragma unroll
    for (int i = 0; i < 64; ++i) sq[i] = x[i] * x[i];
    float s[16];
#pragma unroll
    for (int l = 0; l < 16; ++l) s[l] = (sq[l] + sq[l + 16]) + (sq[l + 32] + sq[l + 48]);
    float t[8];
#pragma unroll
    for (int l = 0; l < 8; ++l) t[l] = s[l] + s[l + 8];
    float u[4];
#pragma unroll
    for (int l = 0; l < 4; ++l) u[l] = t[l] + t[l + 4];
    float v0 = u[0] + u[2];
    float v1 = u[1] + u[3];
    return v0 + v1;
}

// sorted-triple insert, strict < (ties keep earlier-inserted = lower index,
// matching jax.lax.top_k stable tie-breaking when fed in ascending index order)
__device__ __forceinline__ void top3_insert(float d, int j,
                                            float& v0, float& v1, float& v2,
                                            int& i0, int& i1, int& i2) {
    bool b0 = d < v0, b1 = d < v1, b2 = d < v2;
    v2 = b1 ? v1 : (b2 ? d : v2);
    i2 = b1 ? i1 : (b2 ? j : i2);
    v1 = b0 ? v0 : (b1 ? d : v1);
    i1 = b0 ? i0 : (b1 ? j : i1);
    v0 = b0 ? d : v0;
    i0 = b0 ? j : i0;
}

// ---------------------------------------------------------------------------
// B[j] = np.sum(emb[j]**2) (exact tree emulation) + zero hist/lossAcc
// (replaces the separate hipMemsetAsync — one fewer dispatch).
// ---------------------------------------------------------------------------
__global__ __launch_bounds__(256) void prep_kernel(const float* __restrict__ emb,
                                                   float* __restrict__ B,
                                                   int* __restrict__ hist,
                                                   float* __restrict__ lossAcc) {
    int j = blockIdx.x * 256 + threadIdx.x;
    if (j >= CB) return;
    float e[64];
    const float4* e4 = (const float4*)(emb + (size_t)j * 64);
#pragma unroll
    for (int k = 0; k < 16; ++k) {
        float4 v = e4[k];
        e[4 * k] = v.x; e[4 * k + 1] = v.y; e[4 * k + 2] = v.z; e[4 * k + 3] = v.w;
    }
    B[j] = tree_sum64_sq(e);
    hist[j] = 0;
    if (j == 0) *lossAcc = 0.0f;
}

// ---------------------------------------------------------------------------
// Fused score + merge + epilogue.
// Block = 256 threads = 4 waves. Wave w scores split w for the block's 64 rows
// (thread t: row = bid*64 + (t&63), split = t>>6 — wave-uniform split, so emb
// and B loads stay scalar). Split-partial triples go through LDS; wave 0 then
// merges in ascending split order (identical tie semantics to the old
// merge_kernel) and runs the per-row epilogue with its zr[] STILL IN REGISTERS
// (no z re-read, no 12.6 MB scratch round-trip through out3).
// All FP orderings identical to the previous verified kernel.
// ---------------------------------------------------------------------------
__global__ __launch_bounds__(256) void fused_kernel(const float* __restrict__ z,
                                                    const float* __restrict__ emb,
                                                    const float* __restrict__ B,
                                                    float* __restrict__ out0,
                                                    float* __restrict__ out4,
                                                    int* __restrict__ hist,
                                                    float* __restrict__ lossAcc) {
    __shared__ float sD[SPLITS][64][3];
    __shared__ int   sI[SPLITS][64][3];

    int t = threadIdx.x;
    int r = t & 63;
    int split = t >> 6;                       // wave-uniform
    int row = blockIdx.x * 64 + r;

    float zr[64];
    const float4* z4 = (const float4*)(z + (size_t)row * 64);
#pragma unroll
    for (int k = 0; k < 16; ++k) {
        float4 v = z4[k];
        zr[4 * k] = v.x; zr[4 * k + 1] = v.y; zr[4 * k + 2] = v.z; zr[4 * k + 3] = v.w;
    }
    float A = tree_sum64_sq(zr);

    float v0 = 3.402823466e38f, v1 = 3.402823466e38f, v2 = 3.402823466e38f;
    int i0 = 0, i1 = 0, i2 = 0;
    int jbase = split * JS;

    for (int jj = 0; jj < JS; ++jj) {
        int j = jbase + jj;                   // uniform across the wave
        const float4* e4 = (const float4*)(emb + (size_t)j * 64);
        float Bj = B[j];                      // uniform -> scalar load
        float acc = 0.0f;
#pragma unroll
        for (int k = 0; k < 16; ++k) {
            float4 e = e4[k];                 // uniform -> scalar loads
            acc = fmaf(zr[4 * k],     e.x, acc);
            acc = fmaf(zr[4 * k + 1], e.y, acc);
            acc = fmaf(zr[4 * k + 2], e.z, acc);
            acc = fmaf(zr[4 * k + 3], e.w, acc);
        }
        float d = (A + Bj) - 2.0f * acc;      // fma-contraction bit-identical
        top3_insert(d, j, v0, v1, v2, i0, i1, i2);
    }

    sD[split][r][0] = v0; sD[split][r][1] = v1; sD[split][r][2] = v2;
    sI[split][r][0] = i0; sI[split][r][1] = i1; sI[split][r][2] = i2;
    __syncthreads();

    if (t < 64) {                             // wave 0: zr holds row's z (split 0)
        float m0 = 3.402823466e38f, m1 = 3.402823466e38f, m2 = 3.402823466e38f;
        int j0 = 0, j1 = 0, j2 = 0;
#pragma unroll
        for (int s = 0; s < SPLITS; ++s) {    // ascending split = ascending index
#pragma unroll
            for (int u = 0; u < 3; ++u)
                top3_insert(sD[s][r][u], sI[s][r][u], m0, m1, m2, j0, j1, j2);
        }

        const float4* e0q = (const float4*)(emb + (size_t)j0 * 64);
        const float4* e1q = (const float4*)(emb + (size_t)j1 * 64);
        const float4* e2q = (const float4*)(emb + (size_t)j2 * 64);
        v4f* o4 = (v4f*)(out0 + (size_t)row * 64);

        float lsum = 0.0f;
#pragma unroll
        for (int k4 = 0; k4 < 16; ++k4) {
            float4 a = e0q[k4], b = e1q[k4], c = e2q[k4];   // vectorized gathers
            float zx = zr[4 * k4], zy = zr[4 * k4 + 1];
            float zz = zr[4 * k4 + 2], zw = zr[4 * k4 + 3];
            v4f st;
            float zq, df;
            zq = ((a.x + b.x) + c.x) / 3.0f; df = zq - zx; st.x = zx + df; lsum = fmaf(df, df, lsum);
            zq = ((a.y + b.y) + c.y) / 3.0f; df = zq - zy; st.y = zy + df; lsum = fmaf(df, df, lsum);
            zq = ((a.z + b.z) + c.z) / 3.0f; df = zq - zz; st.z = zz + df; lsum = fmaf(df, df, lsum);
            zq = ((a.w + b.w) + c.w) / 3.0f; df = zq - zw; st.w = zw + df; lsum = fmaf(df, df, lsum);
            __builtin_nontemporal_store(st, o4 + k4);       // out0 never re-read
        }

        size_t ob = (size_t)row * 3;
        out4[ob]     = (float)j0;
        out4[ob + 1] = (float)j1;
        out4[ob + 2] = (float)j2;
        atomicAdd(&hist[j0], 1);
        atomicAdd(&hist[j1], 1);
        atomicAdd(&hist[j2], 1);

        // wave-level reduce of loss partial, one atomic per wave (1024 total,
        // same count/structure as the previous verified kernel)
#pragma unroll
        for (int off = 32; off >= 1; off >>= 1) lsum += __shfl_down(lsum, off);
        if ((t & 63) == 0) atomicAdd(lossAcc, lsum);
    }
}

// ---------------------------------------------------------------------------
// One-hot fill of the 805 MB encodings output.
// out3 starts at byte offset 16,777,224 == 8 (mod 16): plain float4 stores are
// ALL misaligned (16 of 64 lanes per wave-store cross a 64B line -> split
// transactions). Fix: 2-float head, 50,331,647 ALIGNED float4s, 2-float tail.
// A float4 straddles two slices only when its first col == 1022; handled
// branch-free with a second index load (redundant L1 hit otherwise).
// Grid-stride with 2048 blocks removes the 196k-workgroup dispatch ramp.
// Non-temporal: 805 MB must not wash the 32 MB L2.
// ---------------------------------------------------------------------------
#define OH_GRID 2048
__global__ __launch_bounds__(256) void onehot_kernel(const float* __restrict__ idxf,
                                                     float* __restrict__ out3f) {
    v4f* o4 = (v4f*)(out3f + 2);                       // 16B-aligned base
    const int M = (N_ROWS * 3 * CB - 2) / 4;           // 50331647 aligned float4s
    const int stride = OH_GRID * 256;

    for (int m = blockIdx.x * 256 + threadIdx.x; m < M; m += stride) {
        int e0 = 2 + 4 * m;                            // element index in region
        int s0 = e0 >> 10;                             // slice of elems 0,1
        int c0 = e0 & 1023;                            // c0 == 2 (mod 4), <= 1022
        int s3 = (e0 + 3) >> 10;                       // slice of elems 2,3
        int ia = (int)idxf[s0];
        int ib = (int)idxf[s3];                        // == ia unless c0 == 1022
        v4f v;
        v.x = (c0     == ia) ? 1.0f : 0.0f;
        v.y = (c0 + 1 == ia) ? 1.0f : 0.0f;
        v.z = (((c0 + 2) & 1023) == ib) ? 1.0f : 0.0f;
        v.w = (((c0 + 3) & 1023) == ib) ? 1.0f : 0.0f;
        __builtin_nontemporal_store(v, o4 + m);
    }

    if (blockIdx.x == 0 && threadIdx.x == 0) {         // head + tail scalars
        int ia = (int)idxf[0];
        out3f[0] = (ia == 0) ? 1.0f : 0.0f;
        out3f[1] = (ia == 1) ? 1.0f : 0.0f;
        int ib = (int)idxf[N_ROWS * 3 - 1];
        out3f[(size_t)N_ROWS * 3 * CB - 2] = (ib == 1022) ? 1.0f : 0.0f;
        out3f[(size_t)N_ROWS * 3 * CB - 1] = (ib == 1023) ? 1.0f : 0.0f;
    }
}

// ---------------------------------------------------------------------------
// Perplexity from histogram + loss finalize (unchanged).
// ---------------------------------------------------------------------------
__global__ __launch_bounds__(256) void finalize_kernel(const int* __restrict__ hist,
                                                       const float* __restrict__ lossAcc,
                                                       float* __restrict__ out1,
                                                       float* __restrict__ out2) {
    __shared__ float red[256];
    int t = threadIdx.x;
    float local = 0.0f;
    for (int b = t; b < CB; b += 256) {
        float em = (float)hist[b] / 196608.0f;
        local += em * logf(em + 1e-10f);
    }
    red[t] = local;
    __syncthreads();
    for (int s = 128; s >= 1; s >>= 1) {
        if (t < s) red[t] += red[t + s];
        __syncthreads();
    }
    if (t == 0) {
        *out2 = expf(-red[0]);
        float m = *lossAcc / 4194304.0f;
        *out1 = 0.25f * m + m;     // BETA_C*mse + mse
    }
}

extern "C" void kernel_launch(void* const* d_in, const int* in_sizes, int n_in,
                              void* d_out, int out_size, void* d_ws, size_t ws_size,
                              hipStream_t stream) {
    const float* z   = (const float*)d_in[0];   // [16,64,64,64] -> 65536 x 64
    const float* emb = (const float*)d_in[1];   // [1024, 64]

    float* out  = (float*)d_out;
    float* out0 = out;                                    // z_q_st  4194304
    float* out1 = out + 4194304;                          // loss    1
    float* out2 = out + 4194305;                          // perplexity 1
    float* out3 = out + 4194306;                          // encodings 201326592
    float* out4 = out + 4194306 + 201326592ll;            // topk_idx (as float) 196608

    int*   hist    = (int*)d_ws;                          // 1024 ints @ 0
    float* lossAcc = (float*)((char*)d_ws + 4096);        // 1 float
    float* B       = (float*)((char*)d_ws + 8192);        // 1024 floats

    prep_kernel<<<4, 256, 0, stream>>>(emb, B, hist, lossAcc);
    fused_kernel<<<N_ROWS / 64, 256, 0, stream>>>(z, emb, B, out0, out4,
                                                  hist, lossAcc);
    onehot_kernel<<<OH_GRID, 256, 0, stream>>>(out4, out3);
    finalize_kernel<<<1, 256, 0, stream>>>(hist, lossAcc, out1, out2);
}

// Round 2
// 1081.821 us; speedup vs baseline: 1.2963x; 1.2963x over previous
//
#include <hip/hip_runtime.h>
#include <math.h>

#define N_ROWS 65536
#define CB 1024
#define SPLITS 4
#define JS (CB / SPLITS)   // 256 codebook entries per split

typedef float v4f __attribute__((ext_vector_type(4)));

// ---------------------------------------------------------------------------
// Exact emulation of numpy's pairwise_sum for n=64 fp32 (AVX-512 path):
//   r0..r3 = 16-lane vector loads; sum = (r0+r1)+(r2+r3);
//   then _mm512_reduce_add_ps tree: fold at lane distance 8, 4, 2, 1.
// fp contract OFF so the squares are not fused into the adds.
// ---------------------------------------------------------------------------
__device__ __forceinline__ float tree_sum64_sq(const float* x) {
#pragma clang fp contract(off)
    float sq[64];
#pragma unroll
    for (int i = 0; i < 64; ++i) sq[i] = x[i] * x[i];
    float s[16];
#pragma unroll
    for (int l = 0; l < 16; ++l) s[l] = (sq[l] + sq[l + 16]) + (sq[l + 32] + sq[l + 48]);
    float t[8];
#pragma unroll
    for (int l = 0; l < 8; ++l) t[l] = s[l] + s[l + 8];
    float u[4];
#pragma unroll
    for (int l = 0; l < 4; ++l) u[l] = t[l] + t[l + 4];
    float v0 = u[0] + u[2];
    float v1 = u[1] + u[3];
    return v0 + v1;
}

// sorted-triple insert, strict < (ties keep earlier-inserted = lower index,
// matching jax.lax.top_k stable tie-breaking when fed in ascending index order)
__device__ __forceinline__ void top3_insert(float d, int j,
                                            float& v0, float& v1, float& v2,
                                            int& i0, int& i1, int& i2) {
    bool b0 = d < v0, b1 = d < v1, b2 = d < v2;
    v2 = b1 ? v1 : (b2 ? d : v2);
    i2 = b1 ? i1 : (b2 ? j : i2);
    v1 = b0 ? v0 : (b1 ? d : v1);
    i1 = b0 ? i0 : (b1 ? j : i1);
    v0 = b0 ? d : v0;
    i0 = b0 ? j : i0;
}

// ---------------------------------------------------------------------------
// B[j] = np.sum(emb[j]**2) (exact tree emulation) + zero hist/lossAcc
// (replaces the separate hipMemsetAsync — one fewer dispatch).
// ---------------------------------------------------------------------------
__global__ __launch_bounds__(256) void prep_kernel(const float* __restrict__ emb,
                                                   float* __restrict__ B,
                                                   int* __restrict__ hist,
                                                   float* __restrict__ lossAcc) {
    int j = blockIdx.x * 256 + threadIdx.x;
    if (j >= CB) return;
    float e[64];
    const float4* e4 = (const float4*)(emb + (size_t)j * 64);
#pragma unroll
    for (int k = 0; k < 16; ++k) {
        float4 v = e4[k];
        e[4 * k] = v.x; e[4 * k + 1] = v.y; e[4 * k + 2] = v.z; e[4 * k + 3] = v.w;
    }
    B[j] = tree_sum64_sq(e);
    hist[j] = 0;
    if (j == 0) *lossAcc = 0.0f;
}

// ---------------------------------------------------------------------------
// Fused score + merge + epilogue.
// Block = 256 threads = 4 waves. Wave w scores split w for the block's 64 rows.
// CRITICAL codegen property (lost in the previous round, restored here):
// `split` must be UNIFORM in the compiler's divergence analysis so that the
// emb/B loads in the j-loop compile to SCALAR loads (s_load_dwordx16 feeding
// v_fmac with SGPR operands). threadIdx.x>>6 is wave-uniform in reality but
// LLVM treats it as divergent -> round 1 emitted per-lane vector loads, blew
// up VGPR pressure next to zr[64], and ran 4x slower (VALUBusy 27%).
// __builtin_amdgcn_readfirstlane is bit-exact here (lanes 0..63 are wave 0 by
// linear workitem->wave packing) and makes the uniformity provable.
// Split-partial triples go through LDS; wave 0 merges in ascending split order
// (identical tie semantics) and runs the epilogue with zr[] still in registers.
// ---------------------------------------------------------------------------
__global__ __launch_bounds__(256) void fused_kernel(const float* __restrict__ z,
                                                    const float* __restrict__ emb,
                                                    const float* __restrict__ B,
                                                    float* __restrict__ out0,
                                                    float* __restrict__ out4,
                                                    int* __restrict__ hist,
                                                    float* __restrict__ lossAcc) {
    __shared__ float sD[SPLITS][64][3];
    __shared__ int   sI[SPLITS][64][3];

    int t = threadIdx.x;
    int r = t & 63;
    int split = __builtin_amdgcn_readfirstlane(t >> 6);   // uniform -> scalar loads
    int row = blockIdx.x * 64 + r;

    float zr[64];
    const float4* z4 = (const float4*)(z + (size_t)row * 64);
#pragma unroll
    for (int k = 0; k < 16; ++k) {
        float4 v = z4[k];
        zr[4 * k] = v.x; zr[4 * k + 1] = v.y; zr[4 * k + 2] = v.z; zr[4 * k + 3] = v.w;
    }
    float A = tree_sum64_sq(zr);

    float v0 = 3.402823466e38f, v1 = 3.402823466e38f, v2 = 3.402823466e38f;
    int i0 = 0, i1 = 0, i2 = 0;
    int jbase = split * JS;

    for (int jj = 0; jj < JS; ++jj) {
        int j = jbase + jj;                   // uniform (split is readfirstlane'd)
        const float4* e4 = (const float4*)(emb + (size_t)j * 64);
        float Bj = B[j];                      // uniform -> scalar load
        float acc = 0.0f;
#pragma unroll
        for (int k = 0; k < 16; ++k) {
            float4 e = e4[k];                 // uniform -> scalar loads
            acc = fmaf(zr[4 * k],     e.x, acc);
            acc = fmaf(zr[4 * k + 1], e.y, acc);
            acc = fmaf(zr[4 * k + 2], e.z, acc);
            acc = fmaf(zr[4 * k + 3], e.w, acc);
        }
        float d = (A + Bj) - 2.0f * acc;      // fma-contraction bit-identical
        top3_insert(d, j, v0, v1, v2, i0, i1, i2);
    }

    sD[split][r][0] = v0; sD[split][r][1] = v1; sD[split][r][2] = v2;
    sI[split][r][0] = i0; sI[split][r][1] = i1; sI[split][r][2] = i2;
    __syncthreads();

    if (t < 64) {                             // wave 0: zr holds row's z (split 0)
        float m0 = 3.402823466e38f, m1 = 3.402823466e38f, m2 = 3.402823466e38f;
        int j0 = 0, j1 = 0, j2 = 0;
#pragma unroll
        for (int s = 0; s < SPLITS; ++s) {    // ascending split = ascending index
#pragma unroll
            for (int u = 0; u < 3; ++u)
                top3_insert(sD[s][r][u], sI[s][r][u], m0, m1, m2, j0, j1, j2);
        }

        const float4* e0q = (const float4*)(emb + (size_t)j0 * 64);
        const float4* e1q = (const float4*)(emb + (size_t)j1 * 64);
        const float4* e2q = (const float4*)(emb + (size_t)j2 * 64);
        v4f* o4 = (v4f*)(out0 + (size_t)row * 64);

        float lsum = 0.0f;
#pragma unroll
        for (int k4 = 0; k4 < 16; ++k4) {
            float4 a = e0q[k4], b = e1q[k4], c = e2q[k4];   // vectorized gathers
            float zx = zr[4 * k4], zy = zr[4 * k4 + 1];
            float zz = zr[4 * k4 + 2], zw = zr[4 * k4 + 3];
            v4f st;
            float zq, df;
            zq = ((a.x + b.x) + c.x) / 3.0f; df = zq - zx; st.x = zx + df; lsum = fmaf(df, df, lsum);
            zq = ((a.y + b.y) + c.y) / 3.0f; df = zq - zy; st.y = zy + df; lsum = fmaf(df, df, lsum);
            zq = ((a.z + b.z) + c.z) / 3.0f; df = zq - zz; st.z = zz + df; lsum = fmaf(df, df, lsum);
            zq = ((a.w + b.w) + c.w) / 3.0f; df = zq - zw; st.w = zw + df; lsum = fmaf(df, df, lsum);
            __builtin_nontemporal_store(st, o4 + k4);       // out0 never re-read
        }

        size_t ob = (size_t)row * 3;
        out4[ob]     = (float)j0;
        out4[ob + 1] = (float)j1;
        out4[ob + 2] = (float)j2;
        atomicAdd(&hist[j0], 1);
        atomicAdd(&hist[j1], 1);
        atomicAdd(&hist[j2], 1);

        // wave-level reduce of loss partial, one atomic per wave
#pragma unroll
        for (int off = 32; off >= 1; off >>= 1) lsum += __shfl_down(lsum, off);
        if ((t & 63) == 0) atomicAdd(lossAcc, lsum);
    }
}

// ---------------------------------------------------------------------------
// One-hot fill of the 805 MB encodings output.
// out3 starts at byte offset 16,777,224 == 8 (mod 16): plain float4 stores are
// ALL misaligned. Fix: 2-float head, aligned float4 body, 2-float tail.
// A float4 straddles two slices only when its first col == 1022; handled
// branch-free with a second index load. Grid-stride with 2048 blocks.
// Non-temporal: 805 MB must not wash the 32 MB L2.
// ---------------------------------------------------------------------------
#define OH_GRID 2048
__global__ __launch_bounds__(256) void onehot_kernel(const float* __restrict__ idxf,
                                                     float* __restrict__ out3f) {
    v4f* o4 = (v4f*)(out3f + 2);                       // 16B-aligned base
    const int M = (N_ROWS * 3 * CB - 2) / 4;           // 50331647 aligned float4s
    const int stride = OH_GRID * 256;

    for (int m = blockIdx.x * 256 + threadIdx.x; m < M; m += stride) {
        int e0 = 2 + 4 * m;                            // element index in region
        int s0 = e0 >> 10;                             // slice of elems 0,1
        int c0 = e0 & 1023;                            // c0 == 2 (mod 4), <= 1022
        int s3 = (e0 + 3) >> 10;                       // slice of elems 2,3
        int ia = (int)idxf[s0];
        int ib = (int)idxf[s3];                        // == ia unless c0 == 1022
        v4f v;
        v.x = (c0     == ia) ? 1.0f : 0.0f;
        v.y = (c0 + 1 == ia) ? 1.0f : 0.0f;
        v.z = (((c0 + 2) & 1023) == ib) ? 1.0f : 0.0f;
        v.w = (((c0 + 3) & 1023) == ib) ? 1.0f : 0.0f;
        __builtin_nontemporal_store(v, o4 + m);
    }

    if (blockIdx.x == 0 && threadIdx.x == 0) {         // head + tail scalars
        int ia = (int)idxf[0];
        out3f[0] = (ia == 0) ? 1.0f : 0.0f;
        out3f[1] = (ia == 1) ? 1.0f : 0.0f;
        int ib = (int)idxf[N_ROWS * 3 - 1];
        out3f[(size_t)N_ROWS * 3 * CB - 2] = (ib == 1022) ? 1.0f : 0.0f;
        out3f[(size_t)N_ROWS * 3 * CB - 1] = (ib == 1023) ? 1.0f : 0.0f;
    }
}

// ---------------------------------------------------------------------------
// Perplexity from histogram + loss finalize (unchanged).
// ---------------------------------------------------------------------------
__global__ __launch_bounds__(256) void finalize_kernel(const int* __restrict__ hist,
                                                       const float* __restrict__ lossAcc,
                                                       float* __restrict__ out1,
                                                       float* __restrict__ out2) {
    __shared__ float red[256];
    int t = threadIdx.x;
    float local = 0.0f;
    for (int b = t; b < CB; b += 256) {
        float em = (float)hist[b] / 196608.0f;
        local += em * logf(em + 1e-10f);
    }
    red[t] = local;
    __syncthreads();
    for (int s = 128; s >= 1; s >>= 1) {
        if (t < s) red[t] += red[t + s];
        __syncthreads();
    }
    if (t == 0) {
        *out2 = expf(-red[0]);
        float m = *lossAcc / 4194304.0f;
        *out1 = 0.25f * m + m;     // BETA_C*mse + mse
    }
}

extern "C" void kernel_launch(void* const* d_in, const int* in_sizes, int n_in,
                              void* d_out, int out_size, void* d_ws, size_t ws_size,
                              hipStream_t stream) {
    const float* z   = (const float*)d_in[0];   // [16,64,64,64] -> 65536 x 64
    const float* emb = (const float*)d_in[1];   // [1024, 64]

    float* out  = (float*)d_out;
    float* out0 = out;                                    // z_q_st  4194304
    float* out1 = out + 4194304;                          // loss    1
    float* out2 = out + 4194305;                          // perplexity 1
    float* out3 = out + 4194306;                          // encodings 201326592
    float* out4 = out + 4194306 + 201326592ll;            // topk_idx (as float) 196608

    int*   hist    = (int*)d_ws;                          // 1024 ints @ 0
    float* lossAcc = (float*)((char*)d_ws + 4096);        // 1 float
    float* B       = (float*)((char*)d_ws + 8192);        // 1024 floats

    prep_kernel<<<4, 256, 0, stream>>>(emb, B, hist, lossAcc);
    fused_kernel<<<N_ROWS / 64, 256, 0, stream>>>(z, emb, B, out0, out4,
                                                  hist, lossAcc);
    onehot_kernel<<<OH_GRID, 256, 0, stream>>>(out4, out3);
    finalize_kernel<<<1, 256, 0, stream>>>(hist, lossAcc, out1, out2);
}

// Round 3
// 1060.564 us; speedup vs baseline: 1.3223x; 1.0200x over previous
//
#include <hip/hip_runtime.h>
#include <math.h>

#define N_ROWS 65536
#define CB 1024
#define SPLITS 4
#define JS (CB / SPLITS)   // 256 codebook entries per split

typedef float v4f __attribute__((ext_vector_type(4)));

// ---------------------------------------------------------------------------
// Exact emulation of numpy's pairwise_sum for n=64 fp32 (AVX-512 path):
//   r0..r3 = 16-lane vector loads; sum = (r0+r1)+(r2+r3);
//   then _mm512_reduce_add_ps tree: fold at lane distance 8, 4, 2, 1.
// fp contract OFF so the squares are not fused into the adds.
// ---------------------------------------------------------------------------
__device__ __forceinline__ float tree_sum64_sq(const float* x) {
#pragma clang fp contract(off)
    float sq[64];
#pragma unroll
    for (int i = 0; i < 64; ++i) sq[i] = x[i] * x[i];
    float s[16];
#pragma unroll
    for (int l = 0; l < 16; ++l) s[l] = (sq[l] + sq[l + 16]) + (sq[l + 32] + sq[l + 48]);
    float t[8];
#pragma unroll
    for (int l = 0; l < 8; ++l) t[l] = s[l] + s[l + 8];
    float u[4];
#pragma unroll
    for (int l = 0; l < 4; ++l) u[l] = t[l] + t[l + 4];
    float v0 = u[0] + u[2];
    float v1 = u[1] + u[3];
    return v0 + v1;
}

// sorted-triple insert, strict < (ties keep earlier-inserted = lower index,
// matching jax.lax.top_k stable tie-breaking when fed in ascending index order)
__device__ __forceinline__ void top3_insert(float d, int j,
                                            float& v0, float& v1, float& v2,
                                            int& i0, int& i1, int& i2) {
    bool b0 = d < v0, b1 = d < v1, b2 = d < v2;
    v2 = b1 ? v1 : (b2 ? d : v2);
    i2 = b1 ? i1 : (b2 ? j : i2);
    v1 = b0 ? v0 : (b1 ? d : v1);
    i1 = b0 ? i0 : (b1 ? j : i1);
    v0 = b0 ? d : v0;
    i0 = b0 ? j : i0;
}

// ---------------------------------------------------------------------------
// B[j] = np.sum(emb[j]**2) (exact tree emulation) + zero hist/lossAcc.
// ---------------------------------------------------------------------------
__global__ __launch_bounds__(256) void prep_kernel(const float* __restrict__ emb,
                                                   float* __restrict__ B,
                                                   int* __restrict__ hist,
                                                   float* __restrict__ lossAcc) {
    int j = blockIdx.x * 256 + threadIdx.x;
    if (j >= CB) return;
    float e[64];
    const float4* e4 = (const float4*)(emb + (size_t)j * 64);
#pragma unroll
    for (int k = 0; k < 16; ++k) {
        float4 v = e4[k];
        e[4 * k] = v.x; e[4 * k + 1] = v.y; e[4 * k + 2] = v.z; e[4 * k + 3] = v.w;
    }
    B[j] = tree_sum64_sq(e);
    hist[j] = 0;
    if (j == 0) *lossAcc = 0.0f;
}

// ---------------------------------------------------------------------------
// Fully fused: score + merge + epilogue + ONE-HOT FILL.
//
// Block = 256 threads = 4 waves; 64 rows per block. Wave w scores split w
// (`split` goes through readfirstlane so the emb/B loads stay provably
// uniform -> scalar s_load path; round 1 showed losing this is 4x).
// #pragma unroll 2 on the j-loop keeps two independent 64-FMA chains in
// flight; per-j FP order (sequential-k single accumulator) is unchanged.
//
// New this round: the block's 64 rows own a CONTIGUOUS 196608-float region
// of out3 (192 one-hot slices). Wave 0's merge publishes the 192 indices to
// LDS; after a barrier all 256 threads stream the region with aligned
// non-temporal float4 stores (region start is always == 8 mod 16 B: 2-float
// head, 49151 aligned float4s, 2-float tail; the c==1022 float4 straddles
// two slices -> second LDS lookup, branch-free). This removes the separate
// onehot dispatch + out4 round-trip and lets the BW-heavy 805 MB store
// stream overlap the VALU-heavy scoring of other resident blocks.
// ---------------------------------------------------------------------------
__global__ __launch_bounds__(256) void fused_kernel(const float* __restrict__ z,
                                                    const float* __restrict__ emb,
                                                    const float* __restrict__ B,
                                                    float* __restrict__ out0,
                                                    float* __restrict__ out3f,
                                                    float* __restrict__ out4,
                                                    int* __restrict__ hist,
                                                    float* __restrict__ lossAcc) {
    __shared__ float sD[SPLITS][64][3];
    __shared__ int   sI[SPLITS][64][3];
    __shared__ int   topk_lds[192];           // 64 rows x 3 slice indices

    int t = threadIdx.x;
    int r = t & 63;
    int split = __builtin_amdgcn_readfirstlane(t >> 6);   // uniform -> scalar loads
    int row = blockIdx.x * 64 + r;

    float zr[64];
    const float4* z4 = (const float4*)(z + (size_t)row * 64);
#pragma unroll
    for (int k = 0; k < 16; ++k) {
        float4 v = z4[k];
        zr[4 * k] = v.x; zr[4 * k + 1] = v.y; zr[4 * k + 2] = v.z; zr[4 * k + 3] = v.w;
    }
    float A = tree_sum64_sq(zr);

    float v0 = 3.402823466e38f, v1 = 3.402823466e38f, v2 = 3.402823466e38f;
    int i0 = 0, i1 = 0, i2 = 0;
    int jbase = split * JS;

#pragma unroll 2
    for (int jj = 0; jj < JS; ++jj) {
        int j = jbase + jj;                   // uniform (split is readfirstlane'd)
        const float4* e4 = (const float4*)(emb + (size_t)j * 64);
        float Bj = B[j];                      // uniform -> scalar load
        float acc = 0.0f;
#pragma unroll
        for (int k = 0; k < 16; ++k) {
            float4 e = e4[k];                 // uniform -> scalar loads
            acc = fmaf(zr[4 * k],     e.x, acc);
            acc = fmaf(zr[4 * k + 1], e.y, acc);
            acc = fmaf(zr[4 * k + 2], e.z, acc);
            acc = fmaf(zr[4 * k + 3], e.w, acc);
        }
        float d = (A + Bj) - 2.0f * acc;      // fma-contraction bit-identical
        top3_insert(d, j, v0, v1, v2, i0, i1, i2);
    }

    sD[split][r][0] = v0; sD[split][r][1] = v1; sD[split][r][2] = v2;
    sI[split][r][0] = i0; sI[split][r][1] = i1; sI[split][r][2] = i2;
    __syncthreads();

    if (t < 64) {                             // wave 0: zr holds row's z (split 0)
        float m0 = 3.402823466e38f, m1 = 3.402823466e38f, m2 = 3.402823466e38f;
        int j0 = 0, j1 = 0, j2 = 0;
#pragma unroll
        for (int s = 0; s < SPLITS; ++s) {    // ascending split = ascending index
#pragma unroll
            for (int u = 0; u < 3; ++u)
                top3_insert(sD[s][r][u], sI[s][r][u], m0, m1, m2, j0, j1, j2);
        }

        topk_lds[r * 3]     = j0;             // publish for the one-hot phase
        topk_lds[r * 3 + 1] = j1;
        topk_lds[r * 3 + 2] = j2;

        const float4* e0q = (const float4*)(emb + (size_t)j0 * 64);
        const float4* e1q = (const float4*)(emb + (size_t)j1 * 64);
        const float4* e2q = (const float4*)(emb + (size_t)j2 * 64);
        v4f* o4 = (v4f*)(out0 + (size_t)row * 64);

        float lsum = 0.0f;
#pragma unroll
        for (int k4 = 0; k4 < 16; ++k4) {
            float4 a = e0q[k4], b = e1q[k4], c = e2q[k4];   // vectorized gathers
            float zx = zr[4 * k4], zy = zr[4 * k4 + 1];
            float zz = zr[4 * k4 + 2], zw = zr[4 * k4 + 3];
            v4f st;
            float zq, df;
            zq = ((a.x + b.x) + c.x) / 3.0f; df = zq - zx; st.x = zx + df; lsum = fmaf(df, df, lsum);
            zq = ((a.y + b.y) + c.y) / 3.0f; df = zq - zy; st.y = zy + df; lsum = fmaf(df, df, lsum);
            zq = ((a.z + b.z) + c.z) / 3.0f; df = zq - zz; st.z = zz + df; lsum = fmaf(df, df, lsum);
            zq = ((a.w + b.w) + c.w) / 3.0f; df = zq - zw; st.w = zw + df; lsum = fmaf(df, df, lsum);
            __builtin_nontemporal_store(st, o4 + k4);       // out0 never re-read
        }

        size_t ob = (size_t)row * 3;
        out4[ob]     = (float)j0;
        out4[ob + 1] = (float)j1;
        out4[ob + 2] = (float)j2;
        atomicAdd(&hist[j0], 1);
        atomicAdd(&hist[j1], 1);
        atomicAdd(&hist[j2], 1);

        // wave-level reduce of loss partial, one atomic per wave
#pragma unroll
        for (int off = 32; off >= 1; off >>= 1) lsum += __shfl_down(lsum, off);
        if ((t & 63) == 0) atomicAdd(lossAcc, lsum);
    }
    __syncthreads();                          // topk_lds visible to all waves

    // ---- one-hot fill of this block's contiguous 196608-float out3 region ----
    float* Rb = out3f + (size_t)blockIdx.x * 196608;   // start == 8 mod 16 B
    v4f* R4 = (v4f*)(Rb + 2);                          // 16B-aligned body base
    const int M = (196608 - 2) / 4;                    // 49151 aligned float4s

    for (int m = t; m < M; m += 256) {
        int e  = 2 + 4 * m;                   // element index within region
        int s0 = e >> 10;                     // slice of elems 0,1 (row*3+k)
        int c  = e & 1023;                    // == 2 mod 4, <= 1022
        int s3 = (e + 3) >> 10;               // slice of elems 2,3
        int ia = topk_lds[s0];                // broadcast-friendly LDS reads
        int ib = topk_lds[s3];                // == ia unless c == 1022
        v4f v;
        v.x = (c     == ia) ? 1.0f : 0.0f;
        v.y = (c + 1 == ia) ? 1.0f : 0.0f;
        v.z = (((c + 2) & 1023) == ib) ? 1.0f : 0.0f;
        v.w = (((c + 3) & 1023) == ib) ? 1.0f : 0.0f;
        __builtin_nontemporal_store(v, R4 + m);
    }
    if (t == 0) {                             // head (slice 0, cols 0,1)
        int ia = topk_lds[0];
        Rb[0] = (ia == 0) ? 1.0f : 0.0f;
        Rb[1] = (ia == 1) ? 1.0f : 0.0f;
        int ib = topk_lds[191];               // tail (slice 191, cols 1022,1023)
        Rb[196606] = (ib == 1022) ? 1.0f : 0.0f;
        Rb[196607] = (ib == 1023) ? 1.0f : 0.0f;
    }
}

// ---------------------------------------------------------------------------
// Perplexity from histogram + loss finalize (unchanged).
// ---------------------------------------------------------------------------
__global__ __launch_bounds__(256) void finalize_kernel(const int* __restrict__ hist,
                                                       const float* __restrict__ lossAcc,
                                                       float* __restrict__ out1,
                                                       float* __restrict__ out2) {
    __shared__ float red[256];
    int t = threadIdx.x;
    float local = 0.0f;
    for (int b = t; b < CB; b += 256) {
        float em = (float)hist[b] / 196608.0f;
        local += em * logf(em + 1e-10f);
    }
    red[t] = local;
    __syncthreads();
    for (int s = 128; s >= 1; s >>= 1) {
        if (t < s) red[t] += red[t + s];
        __syncthreads();
    }
    if (t == 0) {
        *out2 = expf(-red[0]);
        float m = *lossAcc / 4194304.0f;
        *out1 = 0.25f * m + m;     // BETA_C*mse + mse
    }
}

extern "C" void kernel_launch(void* const* d_in, const int* in_sizes, int n_in,
                              void* d_out, int out_size, void* d_ws, size_t ws_size,
                              hipStream_t stream) {
    const float* z   = (const float*)d_in[0];   // [16,64,64,64] -> 65536 x 64
    const float* emb = (const float*)d_in[1];   // [1024, 64]

    float* out  = (float*)d_out;
    float* out0 = out;                                    // z_q_st  4194304
    float* out1 = out + 4194304;                          // loss    1
    float* out2 = out + 4194305;                          // perplexity 1
    float* out3 = out + 4194306;                          // encodings 201326592
    float* out4 = out + 4194306 + 201326592ll;            // topk_idx (as float) 196608

    int*   hist    = (int*)d_ws;                          // 1024 ints @ 0
    float* lossAcc = (float*)((char*)d_ws + 4096);        // 1 float
    float* B       = (float*)((char*)d_ws + 8192);        // 1024 floats

    prep_kernel<<<4, 256, 0, stream>>>(emb, B, hist, lossAcc);
    fused_kernel<<<N_ROWS / 64, 256, 0, stream>>>(z, emb, B, out0, out3, out4,
                                                  hist, lossAcc);
    finalize_kernel<<<1, 256, 0, stream>>>(hist, lossAcc, out1, out2);
}